// Round 1
// baseline (966.596 us; speedup 1.0000x reference)
//
#include <hip/hip_runtime.h>
#include <hip/hip_bf16.h>
#include <math.h>

typedef __attribute__((ext_vector_type(8))) short short8;
typedef __attribute__((ext_vector_type(4))) float f32x4;

#define MFMA_BF16 __builtin_amdgcn_mfma_f32_16x16x32_bf16

__device__ __forceinline__ ushort f2bf(float f) {
  union { __hip_bfloat16 h; ushort u; } c;
  c.h = __float2bfloat16(f);
  return c.u;
}

// ---------------- weight fp32 -> bf16 ----------------
__global__ __launch_bounds__(256) void conv_bf16(const float* __restrict__ src,
                                                 ushort* __restrict__ dst, int n4) {
  int i = blockIdx.x * 256 + threadIdx.x;
  if (i < n4) {
    float4 v = ((const float4*)src)[i];
    ushort4 o;
    o.x = f2bf(v.x); o.y = f2bf(v.y); o.z = f2bf(v.z); o.w = f2bf(v.w);
    ((ushort4*)dst)[i] = o;
  }
}

// ---------------- layernorm: one block per 1024-float row -> bf16 ----------------
__global__ __launch_bounds__(256) void ln_kernel(const float* __restrict__ x,
    const float* __restrict__ g, const float* __restrict__ b,
    ushort* __restrict__ out) {
  const int row = blockIdx.x, t = threadIdx.x;
  float4 v = ((const float4*)(x + (size_t)row * 1024))[t];
  float s  = v.x + v.y + v.z + v.w;
  float ss = v.x*v.x + v.y*v.y + v.z*v.z + v.w*v.w;
  #pragma unroll
  for (int off = 32; off >= 1; off >>= 1) {
    s  += __shfl_xor(s, off);
    ss += __shfl_xor(ss, off);
  }
  __shared__ float red[8];
  int wv = t >> 6, ln = t & 63;
  if (ln == 0) { red[wv] = s; red[4 + wv] = ss; }
  __syncthreads();
  float S  = red[0] + red[1] + red[2] + red[3];
  float SS = red[4] + red[5] + red[6] + red[7];
  float mu  = S * (1.0f/1024.0f);
  float var = SS * (1.0f/1024.0f) - mu*mu;
  float rs  = rsqrtf(var + 1e-6f);
  float4 gv = ((const float4*)g)[t];
  float4 bv = ((const float4*)b)[t];
  ushort4 o;
  o.x = f2bf((v.x-mu)*rs*gv.x + bv.x);
  o.y = f2bf((v.y-mu)*rs*gv.y + bv.y);
  o.z = f2bf((v.z-mu)*rs*gv.z + bv.z);
  o.w = f2bf((v.w-mu)*rs*gv.w + bv.w);
  ((ushort4*)(out + (size_t)row*1024))[t] = o;
}

// ---------------- tiled bf16 GEMM: C[m,n] = sum_k A[m,k]*W[n,k] (+bias, epilogue) ----
// A: [M,K] bf16 row-major. Bw: [N,K] bf16 row-major (torch Linear weight layout).
// 128x128 tile, 4 waves, each wave 64x64 via 4x4 grid of 16x16x32 MFMAs.
enum { EPI_QK = 0, EPI_V = 1, EPI_WO = 2, EPI_GELU = 3, EPI_OUT = 4 };

template <int EPI>
__global__ __launch_bounds__(256) void gemm_kernel(const ushort* __restrict__ A,
    const ushort* __restrict__ Bw, const float* __restrict__ bias,
    const float* __restrict__ res, void* __restrict__ outp, int K, int N) {
  __shared__ ushort As[128 * 40];   // pad 32->40 elems: 2-way bank alias only
  __shared__ ushort Bs[128 * 40];
  const int t = threadIdx.x;
  const int m0 = blockIdx.x * 128, n0 = blockIdx.y * 128;
  const int lane = t & 63, wave = t >> 6;
  const int col = lane & 15, quad = lane >> 4;
  const int wrow = (wave >> 1) * 64, wcol = (wave & 1) * 64;
  const int lr = t >> 2, lc = (t & 3) * 8;

  f32x4 acc[4][4];
  #pragma unroll
  for (int i = 0; i < 4; i++)
    #pragma unroll
    for (int j = 0; j < 4; j++)
      acc[i][j] = (f32x4){0.f, 0.f, 0.f, 0.f};

  const ushort* Ag = A  + (size_t)(m0 + lr) * K + lc;
  const ushort* Bg = Bw + (size_t)(n0 + lr) * K + lc;

  for (int k0 = 0; k0 < K; k0 += 32) {
    __syncthreads();
    *(short8*)&As[lr * 40 + lc]        = *(const short8*)(Ag + k0);
    *(short8*)&As[(lr + 64) * 40 + lc] = *(const short8*)(Ag + (size_t)64 * K + k0);
    *(short8*)&Bs[lr * 40 + lc]        = *(const short8*)(Bg + k0);
    *(short8*)&Bs[(lr + 64) * 40 + lc] = *(const short8*)(Bg + (size_t)64 * K + k0);
    __syncthreads();
    short8 af[4], bf[4];
    #pragma unroll
    for (int tm = 0; tm < 4; tm++)
      af[tm] = *(const short8*)&As[(wrow + tm * 16 + col) * 40 + quad * 8];
    #pragma unroll
    for (int tn = 0; tn < 4; tn++)
      bf[tn] = *(const short8*)&Bs[(wcol + tn * 16 + col) * 40 + quad * 8];
    #pragma unroll
    for (int tm = 0; tm < 4; tm++)
      #pragma unroll
      for (int tn = 0; tn < 4; tn++)
        acc[tm][tn] = MFMA_BF16(af[tm], bf[tn], acc[tm][tn], 0, 0, 0);
  }

  // epilogue: C row = m0+wrow+tm*16+quad*4+r, col = n0+wcol+tn*16+col
  #pragma unroll
  for (int tm = 0; tm < 4; tm++) {
    #pragma unroll
    for (int tn = 0; tn < 4; tn++) {
      const int n = n0 + wcol + tn * 16 + col;
      const float bn = bias[n];
      #pragma unroll
      for (int r = 0; r < 4; r++) {
        const int m = m0 + wrow + tm * 16 + quad * 4 + r;
        float v = acc[tm][tn][r] + bn;
        if (EPI == EPI_QK) {
          int bb = m >> 11, s2 = m & 2047, h = n >> 6, hd = n & 63;
          ((ushort*)outp)[(((size_t)(bb * 16 + h) * 2048 + s2) * 64) + hd] = f2bf(v);
        } else if (EPI == EPI_V) {
          int bb = m >> 11, s2 = m & 2047, h = n >> 6, hd = n & 63;
          ((ushort*)outp)[(((size_t)(bb * 16 + h) * 64 + hd) * 2048) + s2] = f2bf(v);
        } else if (EPI == EPI_WO) {
          ((float*)outp)[(size_t)m * N + n] = v + res[(size_t)m * N + n];
        } else if (EPI == EPI_GELU) {
          float gl = 0.5f * v * (1.0f + erff(v * 0.70710678118654752f));
          ((ushort*)outp)[(size_t)m * N + n] = f2bf(gl);
        } else {  // EPI_OUT
          ((float*)outp)[(size_t)m * N + n] = v + res[(size_t)m * N + n];
        }
      }
    }
  }
}

// ---------------- flash attention ----------------
// Q,K: [BH, S, 64] bf16. Vt: [BH, 64, S] bf16. ctx out: [token, 1024] bf16.
// Grid: BH*32 blocks (qtile=64 rows), 256 threads; each wave: 16 q-rows, full flash.
__global__ __launch_bounds__(256) void attn_kernel(const ushort* __restrict__ Qb,
    const ushort* __restrict__ Kb, const ushort* __restrict__ Vt,
    ushort* __restrict__ ctx) {
  const int lane = threadIdx.x & 63, wave = threadIdx.x >> 6;
  const int col = lane & 15, quad = lane >> 4;
  const int bh = blockIdx.x >> 5, qt = blockIdx.x & 31;
  const int qbase = qt * 64 + wave * 16;
  const ushort* Qh = Qb + (size_t)bh * 2048 * 64;
  const ushort* Kh = Kb + (size_t)bh * 2048 * 64;
  const ushort* Vh = Vt + (size_t)bh * 64 * 2048;

  // Q A-fragments for the 16xHD tile (k = d dimension, two 32-chunks)
  short8 qa0 = *(const short8*)(Qh + (size_t)(qbase + col) * 64 + quad * 8);
  short8 qa1 = *(const short8*)(Qh + (size_t)(qbase + col) * 64 + 32 + quad * 8);

  float m_run[4], l_run[4];
  f32x4 O[4];
  #pragma unroll
  for (int r = 0; r < 4; r++) { m_run[r] = -1e30f; l_run[r] = 0.f; }
  #pragma unroll
  for (int tt = 0; tt < 4; tt++) O[tt] = (f32x4){0.f, 0.f, 0.f, 0.f};

  __shared__ ushort P_lds[4][16][32];
  ushort(*P)[32] = P_lds[wave];

  for (int kb = 0; kb < 2048; kb += 32) {
    // scores: two 16x16 tiles (keys kb..kb+15, kb+16..kb+31), K-dim = d = 64
    f32x4 s0 = (f32x4){0.f, 0.f, 0.f, 0.f};
    f32x4 s1 = (f32x4){0.f, 0.f, 0.f, 0.f};
    {
      const ushort* K0 = Kh + (size_t)(kb + col) * 64;
      s0 = MFMA_BF16(qa0, *(const short8*)(K0 + quad * 8), s0, 0, 0, 0);
      s0 = MFMA_BF16(qa1, *(const short8*)(K0 + 32 + quad * 8), s0, 0, 0, 0);
      const ushort* K1 = Kh + (size_t)(kb + 16 + col) * 64;
      s1 = MFMA_BF16(qa0, *(const short8*)(K1 + quad * 8), s1, 0, 0, 0);
      s1 = MFMA_BF16(qa1, *(const short8*)(K1 + 32 + quad * 8), s1, 0, 0, 0);
    }
    float tmax[4], alpha[4], p0[4], p1[4], psum[4];
    #pragma unroll
    for (int r = 0; r < 4; r++) {
      s0[r] *= 0.125f; s1[r] *= 0.125f;     // 1/sqrt(64)
      tmax[r] = fmaxf(s0[r], s1[r]);
    }
    #pragma unroll
    for (int off = 1; off < 16; off <<= 1)
      #pragma unroll
      for (int r = 0; r < 4; r++)
        tmax[r] = fmaxf(tmax[r], __shfl_xor(tmax[r], off));
    #pragma unroll
    for (int r = 0; r < 4; r++) {
      float mn = fmaxf(m_run[r], tmax[r]);
      alpha[r] = expf(m_run[r] - mn);
      p0[r] = expf(s0[r] - mn);
      p1[r] = expf(s1[r] - mn);
      psum[r] = p0[r] + p1[r];
      m_run[r] = mn;
    }
    #pragma unroll
    for (int off = 1; off < 16; off <<= 1)
      #pragma unroll
      for (int r = 0; r < 4; r++)
        psum[r] += __shfl_xor(psum[r], off);
    #pragma unroll
    for (int r = 0; r < 4; r++) l_run[r] = l_run[r] * alpha[r] + psum[r];
    // P: C-layout -> LDS -> A-layout (wave-private; in-wave DS ordering suffices)
    #pragma unroll
    for (int r = 0; r < 4; r++) {
      P[quad * 4 + r][col]      = f2bf(p0[r]);
      P[quad * 4 + r][16 + col] = f2bf(p1[r]);
    }
    #pragma unroll
    for (int tt = 0; tt < 4; tt++)
      #pragma unroll
      for (int r = 0; r < 4; r++)
        O[tt][r] *= alpha[r];
    short8 pf = *(const short8*)&P[col][quad * 8];
    #pragma unroll
    for (int tt = 0; tt < 4; tt++) {
      short8 vf = *(const short8*)(Vh + (size_t)(tt * 16 + col) * 2048 + kb + quad * 8);
      O[tt] = MFMA_BF16(pf, vf, O[tt], 0, 0, 0);
    }
  }

  const int bb = bh >> 4, h = bh & 15;
  #pragma unroll
  for (int r = 0; r < 4; r++) {
    float inv = 1.0f / l_run[r];
    int q = qbase + quad * 4 + r;
    size_t base = ((size_t)(bb * 2048 + q)) * 1024 + h * 64;
    #pragma unroll
    for (int tt = 0; tt < 4; tt++)
      ctx[base + tt * 16 + col] = f2bf(O[tt][r] * inv);
  }
}

// ---------------- host ----------------
extern "C" void kernel_launch(void* const* d_in, const int* in_sizes, int n_in,
                              void* d_out, int out_size, void* d_ws, size_t ws_size,
                              hipStream_t stream) {
  const float* x     = (const float*)d_in[0];
  const float* Wq    = (const float*)d_in[1];
  const float* bq    = (const float*)d_in[2];
  const float* Wk    = (const float*)d_in[3];
  const float* bk    = (const float*)d_in[4];
  const float* Wv    = (const float*)d_in[5];
  const float* bv    = (const float*)d_in[6];
  const float* Wo    = (const float*)d_in[7];
  const float* bo    = (const float*)d_in[8];
  const float* W1    = (const float*)d_in[9];
  const float* b1    = (const float*)d_in[10];
  const float* W2    = (const float*)d_in[11];
  const float* b2    = (const float*)d_in[12];
  const float* ln1_g = (const float*)d_in[13];
  const float* ln1_b = (const float*)d_in[14];
  const float* ln2_g = (const float*)d_in[15];
  const float* ln2_b = (const float*)d_in[16];

  const size_t MB = 1ull << 20;
  char* ws = (char*)d_ws;
  ushort* Wq_b = (ushort*)(ws + 0 * MB);
  ushort* Wk_b = (ushort*)(ws + 2 * MB);
  ushort* Wv_b = (ushort*)(ws + 4 * MB);
  ushort* Wo_b = (ushort*)(ws + 6 * MB);
  ushort* W1_b = (ushort*)(ws + 8 * MB);
  ushort* W2_b = (ushort*)(ws + 16 * MB);
  ushort* xn1  = (ushort*)(ws + 24 * MB);
  ushort* Qb   = (ushort*)(ws + 40 * MB);
  ushort* Kb   = (ushort*)(ws + 56 * MB);
  ushort* Vt   = (ushort*)(ws + 72 * MB);
  ushort* ctxb = (ushort*)(ws + 88 * MB);
  float*  x2   = (float*)(ws + 104 * MB);
  ushort* xn2  = (ushort*)(ws + 136 * MB);
  ushort* y1   = (ushort*)(ws + 152 * MB);
  // end: 216 MB

  // weights -> bf16
  conv_bf16<<<1024, 256, 0, stream>>>(Wq, Wq_b, 262144);
  conv_bf16<<<1024, 256, 0, stream>>>(Wk, Wk_b, 262144);
  conv_bf16<<<1024, 256, 0, stream>>>(Wv, Wv_b, 262144);
  conv_bf16<<<1024, 256, 0, stream>>>(Wo, Wo_b, 262144);
  conv_bf16<<<4096, 256, 0, stream>>>(W1, W1_b, 1048576);
  conv_bf16<<<4096, 256, 0, stream>>>(W2, W2_b, 1048576);

  // LN1
  ln_kernel<<<8192, 256, 0, stream>>>(x, ln1_g, ln1_b, xn1);

  // Q/K/V projections
  gemm_kernel<EPI_QK><<<dim3(64, 8), 256, 0, stream>>>(xn1, Wq_b, bq, nullptr, Qb, 1024, 1024);
  gemm_kernel<EPI_QK><<<dim3(64, 8), 256, 0, stream>>>(xn1, Wk_b, bk, nullptr, Kb, 1024, 1024);
  gemm_kernel<EPI_V ><<<dim3(64, 8), 256, 0, stream>>>(xn1, Wv_b, bv, nullptr, Vt, 1024, 1024);

  // attention
  attn_kernel<<<4 * 16 * 32, 256, 0, stream>>>(Qb, Kb, Vt, ctxb);

  // Wo projection + residual -> x2 (fp32)
  gemm_kernel<EPI_WO><<<dim3(64, 8), 256, 0, stream>>>(ctxb, Wo_b, bo, x, x2, 1024, 1024);

  // LN2
  ln_kernel<<<8192, 256, 0, stream>>>(x2, ln2_g, ln2_b, xn2);

  // MLP
  gemm_kernel<EPI_GELU><<<dim3(64, 32), 256, 0, stream>>>(xn2, W1_b, b1, nullptr, y1, 1024, 4096);
  gemm_kernel<EPI_OUT ><<<dim3(64, 8), 256, 0, stream>>>(y1, W2_b, b2, x2, d_out, 4096, 1024);
}

// Round 2
// 928.879 us; speedup vs baseline: 1.0406x; 1.0406x over previous
//
#include <hip/hip_runtime.h>
#include <hip/hip_bf16.h>
#include <math.h>

typedef __attribute__((ext_vector_type(8))) short short8;
typedef __attribute__((ext_vector_type(4))) float f32x4;

#define MFMA_BF16 __builtin_amdgcn_mfma_f32_16x16x32_bf16

__device__ __forceinline__ ushort f2bf(float f) {
  union { __hip_bfloat16 h; ushort u; } c;
  c.h = __float2bfloat16(f);
  return c.u;
}
__device__ __forceinline__ uint pack_bf16(float a, float b) {
  return (uint)f2bf(a) | ((uint)f2bf(b) << 16);
}
__device__ __forceinline__ void async_cp16(const ushort* g, ushort* l) {
  __builtin_amdgcn_global_load_lds(
      (const __attribute__((address_space(1))) void*)g,
      (__attribute__((address_space(3))) void*)l, 16, 0, 0);
}

// ---------------- weight fp32 -> bf16 ----------------
__global__ __launch_bounds__(256) void conv_bf16(const float* __restrict__ src,
                                                 ushort* __restrict__ dst, int n4) {
  int i = blockIdx.x * 256 + threadIdx.x;
  if (i < n4) {
    float4 v = ((const float4*)src)[i];
    ushort4 o;
    o.x = f2bf(v.x); o.y = f2bf(v.y); o.z = f2bf(v.z); o.w = f2bf(v.w);
    ((ushort4*)dst)[i] = o;
  }
}

// ---------------- layernorm: one block per 1024-float row -> bf16 ----------------
__global__ __launch_bounds__(256) void ln_kernel(const float* __restrict__ x,
    const float* __restrict__ g, const float* __restrict__ b,
    ushort* __restrict__ out) {
  const int row = blockIdx.x, t = threadIdx.x;
  float4 v = ((const float4*)(x + (size_t)row * 1024))[t];
  float s  = v.x + v.y + v.z + v.w;
  float ss = v.x*v.x + v.y*v.y + v.z*v.z + v.w*v.w;
  #pragma unroll
  for (int off = 32; off >= 1; off >>= 1) {
    s  += __shfl_xor(s, off);
    ss += __shfl_xor(ss, off);
  }
  __shared__ float red[8];
  int wv = t >> 6, ln = t & 63;
  if (ln == 0) { red[wv] = s; red[4 + wv] = ss; }
  __syncthreads();
  float S  = red[0] + red[1] + red[2] + red[3];
  float SS = red[4] + red[5] + red[6] + red[7];
  float mu  = S * (1.0f/1024.0f);
  float var = SS * (1.0f/1024.0f) - mu*mu;
  float rs  = rsqrtf(var + 1e-6f);
  float4 gv = ((const float4*)g)[t];
  float4 bv = ((const float4*)b)[t];
  ushort4 o;
  o.x = f2bf((v.x-mu)*rs*gv.x + bv.x);
  o.y = f2bf((v.y-mu)*rs*gv.y + bv.y);
  o.z = f2bf((v.z-mu)*rs*gv.z + bv.z);
  o.w = f2bf((v.w-mu)*rs*gv.w + bv.w);
  ((ushort4*)(out + (size_t)row*1024))[t] = o;
}

// ---------------- tiled bf16 GEMM: C[m,n] = sum_k A[m,k]*W[n,k] (+bias, epilogue) ----
// m97-style: unpadded LDS + global_load_lds width=16 staging. 128x128 tile, BK=32,
// 4 waves, each wave 64x64 via 4x4 grid of 16x16x32 MFMAs.
enum { EPI_QK = 0, EPI_V = 1, EPI_WO = 2, EPI_GELU = 3, EPI_OUT = 4 };

template <int EPI>
__global__ __launch_bounds__(256) void gemm_kernel(const ushort* __restrict__ A,
    const ushort* __restrict__ Bw, const float* __restrict__ bias,
    const float* __restrict__ res, void* __restrict__ outp, int K, int N) {
  __shared__ ushort As[128 * 32];   // unpadded: required by global_load_lds lane mapping
  __shared__ ushort Bs[128 * 32];
  const int t = threadIdx.x;
  const int m0 = blockIdx.x * 128, n0 = blockIdx.y * 128;
  const int lane = t & 63, wave = t >> 6;
  const int col = lane & 15, quad = lane >> 4;
  const int wrow = (wave >> 1) * 64, wcol = (wave & 1) * 64;

  f32x4 acc[4][4];
  #pragma unroll
  for (int i = 0; i < 4; i++)
    #pragma unroll
    for (int j = 0; j < 4; j++)
      acc[i][j] = (f32x4){0.f, 0.f, 0.f, 0.f};

  // staging: wave w covers rows w*32..w*32+31 of both tiles, 2 instrs each
  const int lrow = lane >> 2, lcol = (lane & 3) * 8;
  const ushort* Ag = A  + (size_t)(m0 + wave * 32 + lrow) * K + lcol;
  const ushort* Bg = Bw + (size_t)(n0 + wave * 32 + lrow) * K + lcol;
  ushort* ldsA = &As[(wave * 32) * 32];
  ushort* ldsB = &Bs[(wave * 32) * 32];

  for (int k0 = 0; k0 < K; k0 += 32) {
    __syncthreads();
    async_cp16(Ag + k0,                  ldsA);
    async_cp16(Ag + (size_t)16 * K + k0, ldsA + 16 * 32);
    async_cp16(Bg + k0,                  ldsB);
    async_cp16(Bg + (size_t)16 * K + k0, ldsB + 16 * 32);
    __syncthreads();
    short8 af[4], bf[4];
    #pragma unroll
    for (int tm = 0; tm < 4; tm++)
      af[tm] = *(const short8*)&As[(wrow + tm * 16 + col) * 32 + quad * 8];
    #pragma unroll
    for (int tn = 0; tn < 4; tn++)
      bf[tn] = *(const short8*)&Bs[(wcol + tn * 16 + col) * 32 + quad * 8];
    #pragma unroll
    for (int tm = 0; tm < 4; tm++)
      #pragma unroll
      for (int tn = 0; tn < 4; tn++)
        acc[tm][tn] = MFMA_BF16(af[tm], bf[tn], acc[tm][tn], 0, 0, 0);
  }

  // epilogue: C row = m0+wrow+tm*16+quad*4+r, col = n0+wcol+tn*16+col
  #pragma unroll
  for (int tm = 0; tm < 4; tm++) {
    #pragma unroll
    for (int tn = 0; tn < 4; tn++) {
      const int n = n0 + wcol + tn * 16 + col;
      const float bn = bias[n];
      #pragma unroll
      for (int r = 0; r < 4; r++) {
        const int m = m0 + wrow + tm * 16 + quad * 4 + r;
        float v = acc[tm][tn][r] + bn;
        if (EPI == EPI_QK) {
          int bb = m >> 11, s2 = m & 2047, h = n >> 6, hd = n & 63;
          ((ushort*)outp)[(((size_t)(bb * 16 + h) * 2048 + s2) * 64) + hd] = f2bf(v);
        } else if (EPI == EPI_V) {
          int bb = m >> 11, s2 = m & 2047, h = n >> 6, hd = n & 63;
          ((ushort*)outp)[(((size_t)(bb * 16 + h) * 64 + hd) * 2048) + s2] = f2bf(v);
        } else if (EPI == EPI_WO) {
          ((float*)outp)[(size_t)m * N + n] = v + res[(size_t)m * N + n];
        } else if (EPI == EPI_GELU) {
          // tanh-form GELU (max |err| vs exact erf form ~3e-4)
          float u = v * 0.7978845608028654f * (1.0f + 0.044715f * v * v);
          float e = __builtin_amdgcn_exp2f(u * 2.885390081777927f);  // e^{2u}
          float th = 1.0f - 2.0f * __builtin_amdgcn_rcpf(e + 1.0f);
          ((ushort*)outp)[(size_t)m * N + n] = f2bf(0.5f * v * (1.0f + th));
        } else {  // EPI_OUT
          ((float*)outp)[(size_t)m * N + n] = v + res[(size_t)m * N + n];
        }
      }
    }
  }
}

// ---------------- flash attention (transposed scores, no-max softmax) ----------------
// Q,K: [BH, S, 64] bf16. Vt: [BH, 64, S] bf16. ctx out: [token, 1024] bf16.
// Grid: BH*32 blocks, 256 threads; each wave owns 16 q-rows.
// Scores computed as St = K·Q^T (C-layout: lane col = q, rows = keys) so the
// softmax denominator is a per-lane accumulation — no in-loop shuffles.
__global__ __launch_bounds__(256) void attn_kernel(const ushort* __restrict__ Qb,
    const ushort* __restrict__ Kb, const ushort* __restrict__ Vt,
    ushort* __restrict__ ctx) {
  const int lane = threadIdx.x & 63, wave = threadIdx.x >> 6;
  const int col = lane & 15, quad = lane >> 4;
  const int bh = blockIdx.x >> 5, qt = blockIdx.x & 31;
  const int qbase = qt * 64 + wave * 16;
  const ushort* Qh = Qb + (size_t)bh * 2048 * 64;
  const ushort* Kh = Kb + (size_t)bh * 2048 * 64;
  const ushort* Vh = Vt + (size_t)bh * 64 * 2048;

  // Q B-fragments (n = q = col, k-dim = d in two 32-chunks)
  short8 qa0 = *(const short8*)(Qh + (size_t)(qbase + col) * 64 + quad * 8);
  short8 qa1 = *(const short8*)(Qh + (size_t)(qbase + col) * 64 + 32 + quad * 8);

  float l_part = 0.f;          // partial denom for q=col over this lane's keys
  f32x4 Ot[4];                 // O^T: lane holds q=col, d = tt*16 + quad*4 + r
  #pragma unroll
  for (int tt = 0; tt < 4; tt++) Ot[tt] = (f32x4){0.f, 0.f, 0.f, 0.f};

  __shared__ ushort P_lds[4][16][40];   // [q][key0..31], stride 40: 16B-aligned reads
  ushort(*P)[40] = P_lds[wave];

  const float c = 0.125f * 1.4426950408889634f;  // log2(e)/sqrt(64)
  const ushort* Kc = Kh + (size_t)col * 64 + quad * 8;
  const ushort* Vc = Vh + (size_t)col * 2048 + quad * 8;

  for (int kb = 0; kb < 2048; kb += 32) {
    const ushort* K0 = Kc + (size_t)kb * 64;
    const ushort* K1 = K0 + 16 * 64;
    f32x4 st0 = (f32x4){0.f, 0.f, 0.f, 0.f};
    f32x4 st1 = (f32x4){0.f, 0.f, 0.f, 0.f};
    st0 = MFMA_BF16(*(const short8*)K0,        qa0, st0, 0, 0, 0);
    st0 = MFMA_BF16(*(const short8*)(K0 + 32), qa1, st0, 0, 0, 0);
    st1 = MFMA_BF16(*(const short8*)K1,        qa0, st1, 0, 0, 0);
    st1 = MFMA_BF16(*(const short8*)(K1 + 32), qa1, st1, 0, 0, 0);
    // p = exp(s/8), no max subtraction (|s| ~< 3 by construction)
    float p0 = __builtin_amdgcn_exp2f(st0[0] * c);
    float p1 = __builtin_amdgcn_exp2f(st0[1] * c);
    float p2 = __builtin_amdgcn_exp2f(st0[2] * c);
    float p3 = __builtin_amdgcn_exp2f(st0[3] * c);
    float p4 = __builtin_amdgcn_exp2f(st1[0] * c);
    float p5 = __builtin_amdgcn_exp2f(st1[1] * c);
    float p6 = __builtin_amdgcn_exp2f(st1[2] * c);
    float p7 = __builtin_amdgcn_exp2f(st1[3] * c);
    l_part += (p0 + p1) + (p2 + p3) + (p4 + p5) + (p6 + p7);
    // P (key, q=col) -> LDS rows [q][key], packed dword writes
    *(uint*)&P[col][quad * 4]          = pack_bf16(p0, p1);
    *(uint*)&P[col][quad * 4 + 2]      = pack_bf16(p2, p3);
    *(uint*)&P[col][16 + quad * 4]     = pack_bf16(p4, p5);
    *(uint*)&P[col][16 + quad * 4 + 2] = pack_bf16(p6, p7);
    // B-frag of P: n = q = col, k = keys quad*8..quad*8+7
    short8 pf = *(const short8*)&P[col][quad * 8];
    const ushort* Vkb = Vc + kb;
    #pragma unroll
    for (int tt = 0; tt < 4; tt++)
      Ot[tt] = MFMA_BF16(*(const short8*)(Vkb + (size_t)tt * 16 * 2048), pf, Ot[tt], 0, 0, 0);
  }

  // denominator: sum partials across the 4 quads holding q=col
  l_part += __shfl_xor(l_part, 16);
  l_part += __shfl_xor(l_part, 32);
  float inv = __builtin_amdgcn_rcpf(l_part);

  const int bb = bh >> 4, h = bh & 15;
  const int q = qbase + col;
  size_t base = ((size_t)(bb * 2048 + q)) * 1024 + h * 64;
  #pragma unroll
  for (int tt = 0; tt < 4; tt++) {
    ushort4 o;
    o.x = f2bf(Ot[tt][0] * inv);
    o.y = f2bf(Ot[tt][1] * inv);
    o.z = f2bf(Ot[tt][2] * inv);
    o.w = f2bf(Ot[tt][3] * inv);
    *(ushort4*)&ctx[base + tt * 16 + quad * 4] = o;
  }
}

// ---------------- host ----------------
extern "C" void kernel_launch(void* const* d_in, const int* in_sizes, int n_in,
                              void* d_out, int out_size, void* d_ws, size_t ws_size,
                              hipStream_t stream) {
  const float* x     = (const float*)d_in[0];
  const float* Wq    = (const float*)d_in[1];
  const float* bq    = (const float*)d_in[2];
  const float* Wk    = (const float*)d_in[3];
  const float* bk    = (const float*)d_in[4];
  const float* Wv    = (const float*)d_in[5];
  const float* bv    = (const float*)d_in[6];
  const float* Wo    = (const float*)d_in[7];
  const float* bo    = (const float*)d_in[8];
  const float* W1    = (const float*)d_in[9];
  const float* b1    = (const float*)d_in[10];
  const float* W2    = (const float*)d_in[11];
  const float* b2    = (const float*)d_in[12];
  const float* ln1_g = (const float*)d_in[13];
  const float* ln1_b = (const float*)d_in[14];
  const float* ln2_g = (const float*)d_in[15];
  const float* ln2_b = (const float*)d_in[16];

  const size_t MB = 1ull << 20;
  char* ws = (char*)d_ws;
  ushort* Wq_b = (ushort*)(ws + 0 * MB);
  ushort* Wk_b = (ushort*)(ws + 2 * MB);
  ushort* Wv_b = (ushort*)(ws + 4 * MB);
  ushort* Wo_b = (ushort*)(ws + 6 * MB);
  ushort* W1_b = (ushort*)(ws + 8 * MB);
  ushort* W2_b = (ushort*)(ws + 16 * MB);
  ushort* xn1  = (ushort*)(ws + 24 * MB);
  ushort* Qb   = (ushort*)(ws + 40 * MB);
  ushort* Kb   = (ushort*)(ws + 56 * MB);
  ushort* Vt   = (ushort*)(ws + 72 * MB);
  ushort* ctxb = (ushort*)(ws + 88 * MB);
  float*  x2   = (float*)(ws + 104 * MB);
  ushort* xn2  = (ushort*)(ws + 136 * MB);
  ushort* y1   = (ushort*)(ws + 152 * MB);
  // end: 216 MB

  conv_bf16<<<1024, 256, 0, stream>>>(Wq, Wq_b, 262144);
  conv_bf16<<<1024, 256, 0, stream>>>(Wk, Wk_b, 262144);
  conv_bf16<<<1024, 256, 0, stream>>>(Wv, Wv_b, 262144);
  conv_bf16<<<1024, 256, 0, stream>>>(Wo, Wo_b, 262144);
  conv_bf16<<<4096, 256, 0, stream>>>(W1, W1_b, 1048576);
  conv_bf16<<<4096, 256, 0, stream>>>(W2, W2_b, 1048576);

  ln_kernel<<<8192, 256, 0, stream>>>(x, ln1_g, ln1_b, xn1);

  gemm_kernel<EPI_QK><<<dim3(64, 8), 256, 0, stream>>>(xn1, Wq_b, bq, nullptr, Qb, 1024, 1024);
  gemm_kernel<EPI_QK><<<dim3(64, 8), 256, 0, stream>>>(xn1, Wk_b, bk, nullptr, Kb, 1024, 1024);
  gemm_kernel<EPI_V ><<<dim3(64, 8), 256, 0, stream>>>(xn1, Wv_b, bv, nullptr, Vt, 1024, 1024);

  attn_kernel<<<4 * 16 * 32, 256, 0, stream>>>(Qb, Kb, Vt, ctxb);

  gemm_kernel<EPI_WO><<<dim3(64, 8), 256, 0, stream>>>(ctxb, Wo_b, bo, x, x2, 1024, 1024);

  ln_kernel<<<8192, 256, 0, stream>>>(x2, ln2_g, ln2_b, xn2);

  gemm_kernel<EPI_GELU><<<dim3(64, 32), 256, 0, stream>>>(xn2, W1_b, b1, nullptr, y1, 1024, 4096);
  gemm_kernel<EPI_OUT ><<<dim3(64, 8), 256, 0, stream>>>(y1, W2_b, b2, x2, d_out, 4096, 1024);
}

// Round 3
// 596.587 us; speedup vs baseline: 1.6202x; 1.5570x over previous
//
#include <hip/hip_runtime.h>
#include <hip/hip_bf16.h>
#include <math.h>

typedef __attribute__((ext_vector_type(8))) short short8;
typedef __attribute__((ext_vector_type(4))) float f32x4;

#define MFMA_BF16 __builtin_amdgcn_mfma_f32_16x16x32_bf16

__device__ __forceinline__ ushort f2bf(float f) {
  union { __hip_bfloat16 h; ushort u; } c;
  c.h = __float2bfloat16(f);
  return c.u;
}
__device__ __forceinline__ uint pack_bf16(float a, float b) {
  return (uint)f2bf(a) | ((uint)f2bf(b) << 16);
}
__device__ __forceinline__ void async_cp16(const ushort* g, ushort* l) {
  __builtin_amdgcn_global_load_lds(
      (const __attribute__((address_space(1))) void*)g,
      (__attribute__((address_space(3))) void*)l, 16, 0, 0);
}

// ---------------- weight fp32 -> bf16 ----------------
__global__ __launch_bounds__(256) void conv_bf16(const float* __restrict__ src,
                                                 ushort* __restrict__ dst, int n4) {
  int i = blockIdx.x * 256 + threadIdx.x;
  if (i < n4) {
    float4 v = ((const float4*)src)[i];
    ushort4 o;
    o.x = f2bf(v.x); o.y = f2bf(v.y); o.z = f2bf(v.z); o.w = f2bf(v.w);
    ((ushort4*)dst)[i] = o;
  }
}

// ---------------- layernorm: one block per 1024-float row -> bf16 ----------------
__global__ __launch_bounds__(256) void ln_kernel(const float* __restrict__ x,
    const float* __restrict__ g, const float* __restrict__ b,
    ushort* __restrict__ out) {
  const int row = blockIdx.x, t = threadIdx.x;
  float4 v = ((const float4*)(x + (size_t)row * 1024))[t];
  float s  = v.x + v.y + v.z + v.w;
  float ss = v.x*v.x + v.y*v.y + v.z*v.z + v.w*v.w;
  #pragma unroll
  for (int off = 32; off >= 1; off >>= 1) {
    s  += __shfl_xor(s, off);
    ss += __shfl_xor(ss, off);
  }
  __shared__ float red[8];
  int wv = t >> 6, ln = t & 63;
  if (ln == 0) { red[wv] = s; red[4 + wv] = ss; }
  __syncthreads();
  float S  = red[0] + red[1] + red[2] + red[3];
  float SS = red[4] + red[5] + red[6] + red[7];
  float mu  = S * (1.0f/1024.0f);
  float var = SS * (1.0f/1024.0f) - mu*mu;
  float rs  = rsqrtf(var + 1e-6f);
  float4 gv = ((const float4*)g)[t];
  float4 bv = ((const float4*)b)[t];
  ushort4 o;
  o.x = f2bf((v.x-mu)*rs*gv.x + bv.x);
  o.y = f2bf((v.y-mu)*rs*gv.y + bv.y);
  o.z = f2bf((v.z-mu)*rs*gv.z + bv.z);
  o.w = f2bf((v.w-mu)*rs*gv.w + bv.w);
  ((ushort4*)(out + (size_t)row*1024))[t] = o;
}

// ---------------- tiled bf16 GEMM: C[m,n] = sum_k A[m,k]*W[n,k] (+bias, epilogue) ----
enum { EPI_QK = 0, EPI_V = 1, EPI_WO = 2, EPI_GELU = 3, EPI_OUT = 4 };

template <int EPI>
__global__ __launch_bounds__(256) void gemm_kernel(const ushort* __restrict__ A,
    const ushort* __restrict__ Bw, const float* __restrict__ bias,
    const float* __restrict__ res, void* __restrict__ outp, int K, int N) {
  __shared__ ushort As[128 * 32];   // unpadded: required by global_load_lds lane mapping
  __shared__ ushort Bs[128 * 32];
  const int t = threadIdx.x;
  const int m0 = blockIdx.x * 128, n0 = blockIdx.y * 128;
  const int lane = t & 63, wave = t >> 6;
  const int col = lane & 15, quad = lane >> 4;
  const int wrow = (wave >> 1) * 64, wcol = (wave & 1) * 64;

  f32x4 acc[4][4];
  #pragma unroll
  for (int i = 0; i < 4; i++)
    #pragma unroll
    for (int j = 0; j < 4; j++)
      acc[i][j] = (f32x4){0.f, 0.f, 0.f, 0.f};

  const int lrow = lane >> 2, lcol = (lane & 3) * 8;
  const ushort* Ag = A  + (size_t)(m0 + wave * 32 + lrow) * K + lcol;
  const ushort* Bg = Bw + (size_t)(n0 + wave * 32 + lrow) * K + lcol;
  ushort* ldsA = &As[(wave * 32) * 32];
  ushort* ldsB = &Bs[(wave * 32) * 32];

  for (int k0 = 0; k0 < K; k0 += 32) {
    __syncthreads();
    async_cp16(Ag + k0,                  ldsA);
    async_cp16(Ag + (size_t)16 * K + k0, ldsA + 16 * 32);
    async_cp16(Bg + k0,                  ldsB);
    async_cp16(Bg + (size_t)16 * K + k0, ldsB + 16 * 32);
    __syncthreads();
    short8 af[4], bf[4];
    #pragma unroll
    for (int tm = 0; tm < 4; tm++)
      af[tm] = *(const short8*)&As[(wrow + tm * 16 + col) * 32 + quad * 8];
    #pragma unroll
    for (int tn = 0; tn < 4; tn++)
      bf[tn] = *(const short8*)&Bs[(wcol + tn * 16 + col) * 32 + quad * 8];
    #pragma unroll
    for (int tm = 0; tm < 4; tm++)
      #pragma unroll
      for (int tn = 0; tn < 4; tn++)
        acc[tm][tn] = MFMA_BF16(af[tm], bf[tn], acc[tm][tn], 0, 0, 0);
  }

  #pragma unroll
  for (int tm = 0; tm < 4; tm++) {
    #pragma unroll
    for (int tn = 0; tn < 4; tn++) {
      const int n = n0 + wcol + tn * 16 + col;
      const float bn = bias[n];
      #pragma unroll
      for (int r = 0; r < 4; r++) {
        const int m = m0 + wrow + tm * 16 + quad * 4 + r;
        float v = acc[tm][tn][r] + bn;
        if (EPI == EPI_QK) {
          int bb = m >> 11, s2 = m & 2047, h = n >> 6, hd = n & 63;
          ((ushort*)outp)[(((size_t)(bb * 16 + h) * 2048 + s2) * 64) + hd] = f2bf(v);
        } else if (EPI == EPI_V) {
          int bb = m >> 11, s2 = m & 2047, h = n >> 6, hd = n & 63;
          ((ushort*)outp)[(((size_t)(bb * 16 + h) * 64 + hd) * 2048) + s2] = f2bf(v);
        } else if (EPI == EPI_WO) {
          ((float*)outp)[(size_t)m * N + n] = v + res[(size_t)m * N + n];
        } else if (EPI == EPI_GELU) {
          float u = v * 0.7978845608028654f * (1.0f + 0.044715f * v * v);
          float e = __builtin_amdgcn_exp2f(u * 2.885390081777927f);  // e^{2u}
          float th = 1.0f - 2.0f * __builtin_amdgcn_rcpf(e + 1.0f);
          ((ushort*)outp)[(size_t)m * N + n] = f2bf(0.5f * v * (1.0f + th));
        } else {  // EPI_OUT
          ((float*)outp)[(size_t)m * N + n] = v + res[(size_t)m * N + n];
        }
      }
    }
  }
}

// ---------------- flash attention v3 ----------------
// Q,K: [BH, S, 64] bf16. Vt: [BH, 64, S] bf16. ctx out: [token, 1024] bf16.
// Grid: 512 blocks (64 heads x 8 q-tiles of 256). 4 waves, each wave owns 64 q.
// XCD-clustered: head = (bx&7)*8 + ((bx>>3)&7) -> all 8 blocks of a head share
// one XCD's L2 (8 heads x 512KB = 4MB = L2). Scores transposed (C cols = q),
// softmax denom = per-lane accumulation, no max subtraction (|s| < ~3).
__global__ __launch_bounds__(256) void attn_kernel(const ushort* __restrict__ Qb,
    const ushort* __restrict__ Kb, const ushort* __restrict__ Vt,
    ushort* __restrict__ ctx) {
  const int lane = threadIdx.x & 63, wave = threadIdx.x >> 6;
  const int col = lane & 15, quad = lane >> 4;
  const int bx = blockIdx.x;
  const int bh = (bx & 7) * 8 + ((bx >> 3) & 7);
  const int qt = bx >> 6;
  const int qbase = qt * 256 + wave * 64;
  const ushort* Qh = Qb + (size_t)bh * 2048 * 64;
  const ushort* Kh = Kb + (size_t)bh * 2048 * 64;
  const ushort* Vh = Vt + (size_t)bh * 64 * 2048;

  // Q B-fragments: qa[qg][c], q = qbase + qg*16 + col, d-chunk c
  short8 qa[4][2];
  #pragma unroll
  for (int qg = 0; qg < 4; qg++) {
    const ushort* Qr = Qh + (size_t)(qbase + qg * 16 + col) * 64 + quad * 8;
    qa[qg][0] = *(const short8*)Qr;
    qa[qg][1] = *(const short8*)(Qr + 32);
  }

  f32x4 Ot[4][4];              // [qg][dt]: O^T, lane q=col, d = dt*16+quad*4+r
  float l_part[4];
  #pragma unroll
  for (int qg = 0; qg < 4; qg++) {
    l_part[qg] = 0.f;
    #pragma unroll
    for (int dt = 0; dt < 4; dt++) Ot[qg][dt] = (f32x4){0.f, 0.f, 0.f, 0.f};
  }

  __shared__ ushort P_lds[4][4][16][40];   // [wave][qg][q][key], stride 40 shorts = 80B
  const float cs = 0.125f * 1.4426950408889634f;   // log2(e)/sqrt(64)

  const ushort* Kc = Kh + (size_t)col * 64 + quad * 8;
  const ushort* Vc = Vh + (size_t)col * 2048 + quad * 8;

  for (int kb = 0; kb < 2048; kb += 32) {
    // K fragments: kf[kt][c] covers keys kb+kt*16.., d-chunk c
    short8 kf[2][2];
    #pragma unroll
    for (int kt = 0; kt < 2; kt++) {
      const ushort* Kr = Kc + (size_t)(kb + kt * 16) * 64;
      kf[kt][0] = *(const short8*)Kr;
      kf[kt][1] = *(const short8*)(Kr + 32);
    }
    // V fragments: vf[dt] = Vt rows d=dt*16+col, keys kb+quad*8..
    short8 vf[4];
    #pragma unroll
    for (int dt = 0; dt < 4; dt++)
      vf[dt] = *(const short8*)(Vc + (size_t)dt * 16 * 2048 + kb);

    // scores (transposed) + exp + P->LDS, per q-group
    #pragma unroll
    for (int qg = 0; qg < 4; qg++) {
      f32x4 s0 = (f32x4){0.f, 0.f, 0.f, 0.f};
      f32x4 s1 = (f32x4){0.f, 0.f, 0.f, 0.f};
      s0 = MFMA_BF16(kf[0][0], qa[qg][0], s0, 0, 0, 0);
      s0 = MFMA_BF16(kf[0][1], qa[qg][1], s0, 0, 0, 0);
      s1 = MFMA_BF16(kf[1][0], qa[qg][0], s1, 0, 0, 0);
      s1 = MFMA_BF16(kf[1][1], qa[qg][1], s1, 0, 0, 0);
      float p0 = __builtin_amdgcn_exp2f(s0[0] * cs);
      float p1 = __builtin_amdgcn_exp2f(s0[1] * cs);
      float p2 = __builtin_amdgcn_exp2f(s0[2] * cs);
      float p3 = __builtin_amdgcn_exp2f(s0[3] * cs);
      float p4 = __builtin_amdgcn_exp2f(s1[0] * cs);
      float p5 = __builtin_amdgcn_exp2f(s1[1] * cs);
      float p6 = __builtin_amdgcn_exp2f(s1[2] * cs);
      float p7 = __builtin_amdgcn_exp2f(s1[3] * cs);
      l_part[qg] += (p0 + p1) + (p2 + p3) + (p4 + p5) + (p6 + p7);
      ushort(*P)[40] = P_lds[wave][qg];
      *(uint*)&P[col][quad * 4]          = pack_bf16(p0, p1);
      *(uint*)&P[col][quad * 4 + 2]      = pack_bf16(p2, p3);
      *(uint*)&P[col][16 + quad * 4]     = pack_bf16(p4, p5);
      *(uint*)&P[col][16 + quad * 4 + 2] = pack_bf16(p6, p7);
    }
    // PV: B-frag of P (n=q=col, k=keys quad*8..), A = Vt fragments
    #pragma unroll
    for (int qg = 0; qg < 4; qg++) {
      short8 pf = *(const short8*)&P_lds[wave][qg][col][quad * 8];
      #pragma unroll
      for (int dt = 0; dt < 4; dt++)
        Ot[qg][dt] = MFMA_BF16(vf[dt], pf, Ot[qg][dt], 0, 0, 0);
    }
  }

  const int bb = bh >> 4, h = bh & 15;
  #pragma unroll
  for (int qg = 0; qg < 4; qg++) {
    float l = l_part[qg];
    l += __shfl_xor(l, 16);
    l += __shfl_xor(l, 32);
    float inv = __builtin_amdgcn_rcpf(l);
    const int q = qbase + qg * 16 + col;
    size_t base = ((size_t)(bb * 2048 + q)) * 1024 + h * 64;
    #pragma unroll
    for (int dt = 0; dt < 4; dt++) {
      ushort4 o;
      o.x = f2bf(Ot[qg][dt][0] * inv);
      o.y = f2bf(Ot[qg][dt][1] * inv);
      o.z = f2bf(Ot[qg][dt][2] * inv);
      o.w = f2bf(Ot[qg][dt][3] * inv);
      *(ushort4*)&ctx[base + dt * 16 + quad * 4] = o;
    }
  }
}

// ---------------- host ----------------
extern "C" void kernel_launch(void* const* d_in, const int* in_sizes, int n_in,
                              void* d_out, int out_size, void* d_ws, size_t ws_size,
                              hipStream_t stream) {
  const float* x     = (const float*)d_in[0];
  const float* Wq    = (const float*)d_in[1];
  const float* bq    = (const float*)d_in[2];
  const float* Wk    = (const float*)d_in[3];
  const float* bk    = (const float*)d_in[4];
  const float* Wv    = (const float*)d_in[5];
  const float* bv    = (const float*)d_in[6];
  const float* Wo    = (const float*)d_in[7];
  const float* bo    = (const float*)d_in[8];
  const float* W1    = (const float*)d_in[9];
  const float* b1    = (const float*)d_in[10];
  const float* W2    = (const float*)d_in[11];
  const float* b2    = (const float*)d_in[12];
  const float* ln1_g = (const float*)d_in[13];
  const float* ln1_b = (const float*)d_in[14];
  const float* ln2_g = (const float*)d_in[15];
  const float* ln2_b = (const float*)d_in[16];

  const size_t MB = 1ull << 20;
  char* ws = (char*)d_ws;
  ushort* Wq_b = (ushort*)(ws + 0 * MB);
  ushort* Wk_b = (ushort*)(ws + 2 * MB);
  ushort* Wv_b = (ushort*)(ws + 4 * MB);
  ushort* Wo_b = (ushort*)(ws + 6 * MB);
  ushort* W1_b = (ushort*)(ws + 8 * MB);
  ushort* W2_b = (ushort*)(ws + 16 * MB);
  ushort* xn1  = (ushort*)(ws + 24 * MB);
  ushort* Qb   = (ushort*)(ws + 40 * MB);
  ushort* Kb   = (ushort*)(ws + 56 * MB);
  ushort* Vt   = (ushort*)(ws + 72 * MB);
  ushort* ctxb = (ushort*)(ws + 88 * MB);
  float*  x2   = (float*)(ws + 104 * MB);
  ushort* xn2  = (ushort*)(ws + 136 * MB);
  ushort* y1   = (ushort*)(ws + 152 * MB);

  conv_bf16<<<1024, 256, 0, stream>>>(Wq, Wq_b, 262144);
  conv_bf16<<<1024, 256, 0, stream>>>(Wk, Wk_b, 262144);
  conv_bf16<<<1024, 256, 0, stream>>>(Wv, Wv_b, 262144);
  conv_bf16<<<1024, 256, 0, stream>>>(Wo, Wo_b, 262144);
  conv_bf16<<<4096, 256, 0, stream>>>(W1, W1_b, 1048576);
  conv_bf16<<<4096, 256, 0, stream>>>(W2, W2_b, 1048576);

  ln_kernel<<<8192, 256, 0, stream>>>(x, ln1_g, ln1_b, xn1);

  gemm_kernel<EPI_QK><<<dim3(64, 8), 256, 0, stream>>>(xn1, Wq_b, bq, nullptr, Qb, 1024, 1024);
  gemm_kernel<EPI_QK><<<dim3(64, 8), 256, 0, stream>>>(xn1, Wk_b, bk, nullptr, Kb, 1024, 1024);
  gemm_kernel<EPI_V ><<<dim3(64, 8), 256, 0, stream>>>(xn1, Wv_b, bv, nullptr, Vt, 1024, 1024);

  attn_kernel<<<512, 256, 0, stream>>>(Qb, Kb, Vt, ctxb);

  gemm_kernel<EPI_WO><<<dim3(64, 8), 256, 0, stream>>>(ctxb, Wo_b, bo, x, x2, 1024, 1024);

  ln_kernel<<<8192, 256, 0, stream>>>(x2, ln2_g, ln2_b, xn2);

  gemm_kernel<EPI_GELU><<<dim3(64, 32), 256, 0, stream>>>(xn2, W1_b, b1, nullptr, y1, 1024, 4096);
  gemm_kernel<EPI_OUT ><<<dim3(64, 8), 256, 0, stream>>>(y1, W2_b, b2, x2, d_out, 4096, 1024);
}